// Round 1
// baseline (2765.063 us; speedup 1.0000x reference)
//
#include <hip/hip_runtime.h>
#include <cstdint>
#include <cstddef>

// SpatialAttention fused pipeline, fp32 baseline (round 1).
//
// Restructuring: out = Sum_k S[b,h,k] * G[b,o,k,w] + x
//   where G[b,o,k,w] = Sum_c w_e[o,c] * D[b,c,k,w],
//         D[b,c,k,w] = lrelu(Sum_j w_fd[c,j] * F[b,j,k,w])
// G lives in d_out (419MB); final stage is in-place per-(b,o) plane.
// Workspace use: ~14.8 MB (avg, max, bm, F, cm, S).

#define SLOPE 0.001f
#define B_    16
#define C_    256
#define H_    160
#define W_    160
#define HW_   25600
#define NPIX_ 409600

__device__ __forceinline__ float lrelu(float v) { return v > 0.f ? v : SLOPE * v; }

// ---------------------------------------------------------------------------
// K1: per-pixel channel reduction: avg, max, Bm = lrelu(w_ab . x)
// grid 1600 x 64 threads, each thread one float4 (4 pixels). 419MB read.
// ---------------------------------------------------------------------------
__global__ void k_reduce(const float* __restrict__ x, const float* __restrict__ w_ab,
                         float* __restrict__ avg, float* __restrict__ mx,
                         float* __restrict__ bm) {
  int idx = blockIdx.x * 64 + threadIdx.x;          // 0 .. NPIX_/4-1
  int b   = idx / (HW_ / 4);
  int p4  = idx - b * (HW_ / 4);
  const float4* xb = (const float4*)x + (size_t)b * C_ * (HW_ / 4) + p4;
  float4 s = make_float4(0.f, 0.f, 0.f, 0.f);
  float4 m = make_float4(-INFINITY, -INFINITY, -INFINITY, -INFINITY);
  float4 d = make_float4(0.f, 0.f, 0.f, 0.f);
#pragma unroll 4
  for (int c = 0; c < C_; ++c) {
    float4 v = xb[(size_t)c * (HW_ / 4)];
    float  wc = w_ab[c];
    s.x += v.x; s.y += v.y; s.z += v.z; s.w += v.w;
    m.x = fmaxf(m.x, v.x); m.y = fmaxf(m.y, v.y);
    m.z = fmaxf(m.z, v.z); m.w = fmaxf(m.w, v.w);
    d.x = fmaf(wc, v.x, d.x); d.y = fmaf(wc, v.y, d.y);
    d.z = fmaf(wc, v.z, d.z); d.w = fmaf(wc, v.w, d.w);
  }
  int o4 = b * (HW_ / 4) + p4;
  const float inv = 1.f / (float)C_;
  ((float4*)avg)[o4] = make_float4(s.x * inv, s.y * inv, s.z * inv, s.w * inv);
  ((float4*)mx)[o4]  = m;
  ((float4*)bm)[o4]  = make_float4(lrelu(d.x), lrelu(d.y), lrelu(d.z), lrelu(d.w));
}

// ---------------------------------------------------------------------------
// K2: S1/S3/S5/S7 convs on AM=(avg,max) + Cm. 16x16 tile + 3-halo in LDS.
// grid (10,10,16) x 256 threads.
// ---------------------------------------------------------------------------
__global__ void k_convs(const float* __restrict__ avg, const float* __restrict__ mx,
                        const float* __restrict__ w1, const float* __restrict__ w3,
                        const float* __restrict__ w5, const float* __restrict__ w7,
                        const float* __restrict__ w_fc,
                        float* __restrict__ F, float* __restrict__ cm) {
  __shared__ float Aa[22][22];
  __shared__ float Am[22][22];
  int b = blockIdx.z, h0 = blockIdx.y * 16, w0 = blockIdx.x * 16;
  int t = threadIdx.x;
  const float* ab = avg + b * HW_;
  const float* mb = mx + b * HW_;
  for (int i = t; i < 22 * 22; i += 256) {
    int ih = i / 22, iw = i - ih * 22;
    int gh = h0 + ih - 3, gw = w0 + iw - 3;
    bool in = ((unsigned)gh < 160u) && ((unsigned)gw < 160u);
    Aa[ih][iw] = in ? ab[gh * 160 + gw] : 0.f;
    Am[ih][iw] = in ? mb[gh * 160 + gw] : 0.f;
  }
  __syncthreads();
  int ty = t >> 4, tx = t & 15;
  float s1 = w1[0] * Aa[ty + 3][tx + 3] + w1[1] * Am[ty + 3][tx + 3];
  float s3 = 0.f, s5 = 0.f, s7 = 0.f;
#pragma unroll
  for (int kh = 0; kh < 3; ++kh)
#pragma unroll
    for (int kw = 0; kw < 3; ++kw)
      s3 += w3[kh * 3 + kw] * Aa[ty + 2 + kh][tx + 2 + kw] +
            w3[9 + kh * 3 + kw] * Am[ty + 2 + kh][tx + 2 + kw];
#pragma unroll
  for (int kh = 0; kh < 5; ++kh)
#pragma unroll
    for (int kw = 0; kw < 5; ++kw)
      s5 += w5[kh * 5 + kw] * Aa[ty + 1 + kh][tx + 1 + kw] +
            w5[25 + kh * 5 + kw] * Am[ty + 1 + kh][tx + 1 + kw];
#pragma unroll
  for (int kh = 0; kh < 7; ++kh)
#pragma unroll
    for (int kw = 0; kw < 7; ++kw)
      s7 += w7[kh * 7 + kw] * Aa[ty + kh][tx + kw] +
            w7[49 + kh * 7 + kw] * Am[ty + kh][tx + kw];
  s1 = lrelu(s1); s3 = lrelu(s3); s5 = lrelu(s5); s7 = lrelu(s7);
  int hw = (h0 + ty) * 160 + (w0 + tx);
  F[(b * 4 + 0) * HW_ + hw] = s1;
  F[(b * 4 + 1) * HW_ + hw] = s3;
  F[(b * 4 + 2) * HW_ + hw] = s5;
  F[(b * 4 + 3) * HW_ + hw] = s7;
  cm[b * HW_ + hw] = lrelu(w_fc[0] * s1 + w_fc[1] * s3 + w_fc[2] * s5 + w_fc[3] * s7);
}

// ---------------------------------------------------------------------------
// K3: logits L[h,k] = Sum_w Bm[b,h,w]*Cm[b,w,k], softmax over k -> S.
// grid (160,16) x 256 threads (160 active).
// ---------------------------------------------------------------------------
__global__ void k_attn(const float* __restrict__ bm, const float* __restrict__ cm,
                       float* __restrict__ S) {
  int h = blockIdx.x, b = blockIdx.y;
  int t = threadIdx.x;
  __shared__ float row[160];
  __shared__ float red[256];
  const float* bmr = bm + b * HW_ + h * 160;
  const float* cmb = cm + b * HW_;
  if (t < 160) row[t] = bmr[t];
  __syncthreads();
  float acc = 0.f;
  if (t < 160) {
    for (int w = 0; w < 160; ++w) acc = fmaf(row[w], cmb[w * 160 + t], acc);
  }
  red[t] = (t < 160) ? acc : -INFINITY;
  __syncthreads();
  for (int s = 128; s > 0; s >>= 1) {
    if (t < s) red[t] = fmaxf(red[t], red[t + s]);
    __syncthreads();
  }
  float mval = red[0];
  __syncthreads();
  float e = (t < 160) ? __expf(acc - mval) : 0.f;
  red[t] = e;
  __syncthreads();
  for (int s = 128; s > 0; s >>= 1) {
    if (t < s) red[t] += red[t + s];
    __syncthreads();
  }
  float inv = 1.f / red[0];
  if (t < 160) S[(b * 160 + h) * 160 + t] = e * inv;
}

// ---------------------------------------------------------------------------
// K4: G = W_e(256x256) @ lrelu(W_fd @ F)  -> stored in d_out.
// GEMM 256 x 409600 x 256. Block: 128(o) x 128(pix) tile, 8x8 per thread,
// k(=c) tiles of 16. D tile recomputed from F (4 rows) per c-tile.
// grid (3200, 2) x 256 threads. 26.8 GMAC.
// ---------------------------------------------------------------------------
__global__ __launch_bounds__(256) void k_gemm_g(
    const float* __restrict__ F, const float* __restrict__ w_fd,
    const float* __restrict__ w_e, float* __restrict__ G) {
  __shared__ float Fl[4][128];
  __shared__ float Wt[16][132];  // [c_local][o_local], padded
  __shared__ float Dt[16][132];  // [c_local][p_local], padded
  int bx = blockIdx.x;           // 0..3199
  int b  = bx / 200;
  int p0 = (bx - b * 200) * 128;
  int ot0 = blockIdx.y * 128;
  int t = threadIdx.x, tx = t & 15, ty = t >> 4;
  for (int i = t; i < 512; i += 256) {
    int j = i >> 7, pp = i & 127;
    Fl[j][pp] = F[(b * 4 + j) * HW_ + p0 + pp];
  }
  float acc[8][8];
#pragma unroll
  for (int i = 0; i < 8; ++i)
#pragma unroll
    for (int j = 0; j < 8; ++j) acc[i][j] = 0.f;

  for (int ct = 0; ct < 256; ct += 16) {
    __syncthreads();  // prev tile reads done; Fl visible on first iter
#pragma unroll
    for (int i = t; i < 2048; i += 256) {  // W tile: w_e[(ot0+o)*256 + ct+cc]
      int o = i >> 4, cc = i & 15;
      Wt[cc][o] = w_e[(ot0 + o) * 256 + ct + cc];
    }
#pragma unroll
    for (int i = t; i < 2048; i += 256) {  // D tile from F
      int cc = i >> 7, pp = i & 127;
      const float* fd = w_fd + (ct + cc) * 4;
      float v = fd[0] * Fl[0][pp] + fd[1] * Fl[1][pp] +
                fd[2] * Fl[2][pp] + fd[3] * Fl[3][pp];
      Dt[cc][pp] = lrelu(v);
    }
    __syncthreads();
#pragma unroll
    for (int kk = 0; kk < 16; ++kk) {
      float aR[8], bR[8];
#pragma unroll
      for (int i = 0; i < 8; ++i) aR[i] = Wt[kk][ty + 16 * i];
#pragma unroll
      for (int j = 0; j < 8; ++j) bR[j] = Dt[kk][tx + 16 * j];
#pragma unroll
      for (int i = 0; i < 8; ++i)
#pragma unroll
        for (int j = 0; j < 8; ++j) acc[i][j] = fmaf(aR[i], bR[j], acc[i][j]);
    }
  }
#pragma unroll
  for (int i = 0; i < 8; ++i) {
    int o = ot0 + ty + 16 * i;
    float* row = G + ((size_t)(b * 256 + o)) * HW_ + p0;
#pragma unroll
    for (int j = 0; j < 8; ++j) row[tx + 16 * j] = acc[i][j];
  }
}

// ---------------------------------------------------------------------------
// K5: out[b,o,h,w] = Sum_k S[b,h,k] * G[b,o,k,w] + x[b,o,h,w], IN PLACE on
// d_out (G plane -> LDS in two 80-row halves, then overwrite). One block per
// (b,o) plane; 160x160x160 matmul, 10x10 per thread. grid 4096 x 256.
// LDS: 80*160*4 + 160*17*4 = 62080 B (2 blocks/CU).
// ---------------------------------------------------------------------------
__global__ __launch_bounds__(256) void k_out_f(
    const float* __restrict__ S, const float* __restrict__ x,
    float* __restrict__ out) {
  __shared__ float Gp[80 * 160];
  __shared__ float St[160 * 17];
  int bo = blockIdx.x;  // b*256 + o
  int b  = bo >> 8;
  int t = threadIdx.x, tx = t & 15, ty = t >> 4;
  const float* g  = out + (size_t)bo * HW_;
  const float* Sb = S + b * HW_;  // 160x160 plane
  float acc[10][10];
#pragma unroll
  for (int i = 0; i < 10; ++i)
#pragma unroll
    for (int j = 0; j < 10; ++j) acc[i][j] = 0.f;
  int h0 = ty * 10, w0 = tx * 10;

  for (int half = 0; half < 2; ++half) {
    __syncthreads();  // prev half's Gp reads done
    for (int i = t; i < 80 * 160; i += 256) Gp[i] = g[half * 12800 + i];
    for (int kt = 0; kt < 80; kt += 16) {
      __syncthreads();  // Gp stores visible / prev St reads done
      for (int i = t; i < 2560; i += 256) {
        int hh = i >> 4, kk = i & 15;
        St[hh * 17 + kk] = Sb[hh * 160 + half * 80 + kt + kk];
      }
      __syncthreads();
#pragma unroll
      for (int kk = 0; kk < 16; ++kk) {
        float aR[10], bR[10];
#pragma unroll
        for (int i = 0; i < 10; ++i) aR[i] = St[(h0 + i) * 17 + kk];
#pragma unroll
        for (int j = 0; j < 10; ++j) bR[j] = Gp[(kt + kk) * 160 + w0 + j];
#pragma unroll
        for (int i = 0; i < 10; ++i)
#pragma unroll
          for (int j = 0; j < 10; ++j) acc[i][j] = fmaf(aR[i], bR[j], acc[i][j]);
      }
    }
  }
  // all global reads of g completed before the last barrier -> safe to overwrite
  const float* xb = x + (size_t)bo * HW_;
  float* ob = out + (size_t)bo * HW_;
#pragma unroll
  for (int i = 0; i < 10; ++i) {
    int h = h0 + i;
#pragma unroll
    for (int j = 0; j < 10; ++j)
      ob[h * 160 + w0 + j] = acc[i][j] + xb[h * 160 + w0 + j];
  }
}

// ---------------------------------------------------------------------------
extern "C" void kernel_launch(void* const* d_in, const int* in_sizes, int n_in,
                              void* d_out, int out_size, void* d_ws, size_t ws_size,
                              hipStream_t stream) {
  const float* x    = (const float*)d_in[0];
  const float* w1   = (const float*)d_in[1];
  const float* w3   = (const float*)d_in[2];
  const float* w5   = (const float*)d_in[3];
  const float* w7   = (const float*)d_in[4];
  const float* w_ab = (const float*)d_in[5];
  const float* w_fc = (const float*)d_in[6];
  const float* w_fd = (const float*)d_in[7];
  const float* w_e  = (const float*)d_in[8];
  float* out = (float*)d_out;

  float* ws  = (float*)d_ws;          // needs 3,686,400 floats = 14.75 MB
  float* avg = ws;                    // 409600
  float* mx  = ws + 409600;           // 409600
  float* bm  = ws + 819200;           // 409600
  float* Fb  = ws + 1228800;          // 1638400 (B,4,H,W)
  float* cm  = ws + 2867200;          // 409600
  float* Sm  = ws + 3276800;          // 409600 (B,160,160)

  k_reduce<<<NPIX_ / 4 / 64, 64, 0, stream>>>(x, w_ab, avg, mx, bm);
  k_convs<<<dim3(10, 10, 16), 256, 0, stream>>>(avg, mx, w1, w3, w5, w7, w_fc, Fb, cm);
  k_attn<<<dim3(160, 16), 256, 0, stream>>>(bm, cm, Sm);
  k_gemm_g<<<dim3(3200, 2), 256, 0, stream>>>(Fb, w_fd, w_e, out);
  k_out_f<<<4096, 256, 0, stream>>>(Sm, x, out);
}